// Round 7
// baseline (3073.390 us; speedup 1.0000x reference)
//
#include <hip/hip_runtime.h>

// ws layout (fp32):
//   Wcx  [7][2048]  @ float offset 0      (57344 B)  xz-feedback fold
//   WtsT [14][1024] @ float offset 14336  (57344 B)  (W_out @ [W_tr|W_se])^T
//   bts  [14]       @ float offset 28672  (56 B)     b_out@[W_tr|W_se]+[b_tr|b_se]
// total 114744 B

// ---------------- one-time weight folds ----------------
__global__ __launch_bounds__(256) void k_fold(
    const float* __restrict__ W_feat, const float* __restrict__ W_inproj,
    const float* __restrict__ Wout, const float* __restrict__ Wtr,
    const float* __restrict__ Wse, const float* __restrict__ b_out,
    const float* __restrict__ b_tr, const float* __restrict__ b_se,
    float* __restrict__ ws) {
  float* Wcx  = ws;
  float* WtsT = ws + 14336;
  float* bts  = ws + 28672;
  const int b = blockIdx.x, t = threadIdx.x;
  if (b < 8) {
    // Wcx[i][j] = sum_k W_feat[512+i][k] * W_inproj[k][j]
    int j = b * 256 + t;
    float acc[7] = {0, 0, 0, 0, 0, 0, 0};
    for (int k = 0; k < 512; ++k) {
      float wi = W_inproj[(size_t)k * 2048 + j];
#pragma unroll
      for (int i = 0; i < 7; ++i) acc[i] += W_feat[(size_t)(512 + i) * 512 + k] * wi;
    }
#pragma unroll
    for (int i = 0; i < 7; ++i) Wcx[i * 2048 + j] = acc[i];
  } else if (b < 12) {
    // WtsT[c][k] = sum_o Wout[k][o] * [Wtr|Wse][o][c]
    int k = (b - 8) * 256 + t;
    float acc[14];
#pragma unroll
    for (int c = 0; c < 14; ++c) acc[c] = 0.f;
    const float* wo = Wout + (size_t)k * 512;
    for (int o = 0; o < 512; ++o) {
      float w = wo[o];
      const float* tr = Wtr + o * 7;
      const float* se = Wse + o * 7;
#pragma unroll
      for (int c = 0; c < 7; ++c) { acc[c] += w * tr[c]; acc[7 + c] += w * se[c]; }
    }
#pragma unroll
    for (int c = 0; c < 14; ++c) WtsT[c * 1024 + k] = acc[c];
  } else {
    if (t < 14) {
      int c = (t < 7) ? t : t - 7;
      const float* W = (t < 7) ? Wtr : Wse;
      float s = (t < 7) ? b_tr[t] : b_se[t - 7];
      for (int o = 0; o < 512; ++o) s += b_out[o] * W[o * 7 + c];
      bts[t] = s;
    }
  }
}

// ---------------- persistent scan: 512 blocks x 1024 thr, 2 rows/block ------
struct Pro {                       // prologue-only
  float hb[2][512];                // h -> fused (in place)      4K
  float hin[2][512];               //                            4K
  float hpart[2][2][512];          // K-split partials           8K
};
struct Sc {                        // scan-phase
  float xc[2][1024];               // x_c, later y (in place)    8K
  float part2[4][2][160];          // P2 K-split partials        5K
  float proj[2][32];               // dt_r reduced             256B
  float combs[2][8];
  float bcv[2];
  float ts[2][16];
};
union SMem { Pro pro; Sc sc; };

__global__ __launch_bounds__(1024, 8) void k_scan(
    const float* __restrict__ tc, const float* __restrict__ cc,
    const float* __restrict__ initv,
    const float* __restrict__ W_cf, const float* __restrict__ b_cf,
    const float* __restrict__ ln_g, const float* __restrict__ ln_b,
    const float* __restrict__ W_feat, const float* __restrict__ b_feat,
    const float* __restrict__ W_inproj, const float* __restrict__ b_inproj,
    const float* __restrict__ conv_w, const float* __restrict__ conv_b,
    const float* __restrict__ Wxp,
    const float* __restrict__ Wdt, const float* __restrict__ b_dt,
    const float* __restrict__ D_param,
    const float* __restrict__ W_fin, const float* __restrict__ b_fin,
    const float* __restrict__ ws, float* __restrict__ out) {
  __shared__ SMem S;
  const float* Wcx_ws  = ws;
  const float* WtsT_ws = ws + 14336;
  const float* bts_ws  = ws + 28672;
  const int t = threadIdx.x;          // 0..1023
  const int r0 = blockIdx.x * 2;
  const int o9 = t & 511;
  const int kc9 = t >> 9;

  // ---- h = relu([tc,cc] @ W_cf + b_cf); kc9 picks tc (k<512) or cc half ----
  {
    const float* src = ((kc9 == 0) ? tc : cc) + (size_t)r0 * 512;
    const float* wp = W_cf + (size_t)(kc9 * 512) * 512 + o9;
    float a0 = 0, a1 = 0;
    for (int k = 0; k < 512; ++k) {
      float w = wp[0]; wp += 512;
      a0 += src[k] * w; a1 += src[512 + k] * w;
    }
    S.pro.hpart[kc9][0][o9] = a0; S.pro.hpart[kc9][1][o9] = a1;
  }
  __syncthreads();
  S.pro.hb[kc9][o9] = fmaxf(S.pro.hpart[0][kc9][o9] + S.pro.hpart[1][kc9][o9] + b_cf[o9], 0.f);
  __syncthreads();
  // ---- LayerNorm (2 rows, waves 0-1) ----
  if (t < 128) {
    int w = t >> 6, lane = t & 63;
    float s = 0.f, s2 = 0.f;
    for (int j = lane; j < 512; j += 64) { float v = S.pro.hb[w][j]; s += v; s2 += v * v; }
#pragma unroll
    for (int off = 32; off; off >>= 1) { s += __shfl_xor(s, off); s2 += __shfl_xor(s2, off); }
    float mu = s * (1.f / 512.f);
    float var = s2 * (1.f / 512.f) - mu * mu;
    float inv = rsqrtf(var + 1e-5f);
    for (int j = lane; j < 512; j += 64)
      S.pro.hb[w][j] = (S.pro.hb[w][j] - mu) * inv * ln_g[j] + ln_b[j];
  }
  __syncthreads();
  // ---- hin = fused @ W_feat[:512] + b_feat (K split 2x256) ----
  {
    int k0 = kc9 * 256;
    const float* wp = W_feat + (size_t)k0 * 512 + o9;
    float a0 = 0, a1 = 0;
    for (int k = k0; k < k0 + 256; ++k) {
      float w = wp[0]; wp += 512;
      a0 += S.pro.hb[0][k] * w; a1 += S.pro.hb[1][k] * w;
    }
    S.pro.hpart[kc9][0][o9] = a0; S.pro.hpart[kc9][1][o9] = a1;
  }
  __syncthreads();
  S.pro.hin[kc9][o9] = S.pro.hpart[0][kc9][o9] + S.pro.hpart[1][kc9][o9] + b_feat[o9];
  __syncthreads();

  // ---- xz_base cols t (x) and 1024+t (z) into registers ----
  float xzbx[2], xzbz[2];
#pragma unroll
  for (int half = 0; half < 2; ++half) {
    int col = t + half * 1024;
    const float* wp = W_inproj + col;
    float a0 = 0, a1 = 0;
    for (int k = 0; k < 512; ++k) {
      float wi = wp[0]; wp += 2048;
      a0 += S.pro.hin[0][k] * wi; a1 += S.pro.hin[1][k] * wi;
    }
    float bi = b_inproj[col];
    if (half == 0) { xzbx[0] = a0 + bi; xzbx[1] = a1 + bi; }
    else           { xzbz[0] = a0 + bi; xzbz[1] = a1 + bi; }
  }

  // ---- step-invariant per-thread constants ----
  float wcxx[7], wcxz[7];
#pragma unroll
  for (int i = 0; i < 7; ++i) {
    wcxx[i] = Wcx_ws[i * 2048 + t];
    wcxz[i] = Wcx_ws[i * 2048 + 1024 + t];
  }
  const float cw3  = conv_w[t * 4 + 3];
  const float cbv  = conv_b[t];
  const float dpar = D_param[t];
  const float bdtv = b_dt[t];

  if (t < 14) S.sc.combs[t / 7][t % 7] = initv[(r0 + t / 7) * 7 + (t % 7)];
  __syncthreads();

  // ================= 64 sequential decode steps =================
  float zsr[2], xcr[2];
  for (int step = 0; step < 64; ++step) {
    // P1: xz = xz_base + comb @ Wcx; x_c = silu(conv) -> LDS+reg; silu(z) -> reg
#pragma unroll
    for (int r = 0; r < 2; ++r) {
      float v = xzbx[r], u = xzbz[r];
#pragma unroll
      for (int i = 0; i < 7; ++i) {
        float cb_ = S.sc.combs[r][i];
        v += cb_ * wcxx[i];
        u += cb_ * wcxz[i];
      }
      v = v * cw3 + cbv;
      float sv = v / (1.f + __expf(-v));
      xcr[r] = sv;
      S.sc.xc[r][t] = sv;
      zsr[r] = u / (1.f + __expf(-u));
    }
    __syncthreads();

    // P2: part2 = x_c @ W_xproj, K=1024 split in 4 (640 threads)
    if (t < 640) {
      int kc = t / 160, p = t - kc * 160;
      const float* wp = Wxp + (size_t)(kc * 256) * 160 + p;
      const float2* x0 = reinterpret_cast<const float2*>(&S.sc.xc[0][kc * 256]);
      const float2* x1 = reinterpret_cast<const float2*>(&S.sc.xc[1][kc * 256]);
      float a0 = 0, a1 = 0;
#pragma unroll 4
      for (int i = 0; i < 128; ++i) {
        float w0 = wp[0], w1 = wp[160];
        wp += 320;
        float2 v0 = x0[i], v1 = x1[i];
        a0 += v0.x * w0 + v0.y * w1;
        a1 += v1.x * w0 + v1.y * w1;
      }
      S.sc.part2[kc][0][p] = a0; S.sc.part2[kc][1][p] = a1;
    }
    __syncthreads();

    // reduce dt_r + bc = <Bm,Cm> (disjoint thread ranges)
    if (t < 64) {
      int r = t >> 5, p = t & 31;
      S.sc.proj[r][p] = S.sc.part2[0][r][p] + S.sc.part2[1][r][p] +
                        S.sc.part2[2][r][p] + S.sc.part2[3][r][p];
    } else if (t >= 256 && t < 384) {
      int r = (t - 256) >> 6, n = t & 63;
      float bm = S.sc.part2[0][r][32 + n] + S.sc.part2[1][r][32 + n] +
                 S.sc.part2[2][r][32 + n] + S.sc.part2[3][r][32 + n];
      float cm = S.sc.part2[0][r][96 + n] + S.sc.part2[1][r][96 + n] +
                 S.sc.part2[2][r][96 + n] + S.sc.part2[3][r][96 + n];
      float pr = bm * cm;
#pragma unroll
      for (int off = 32; off; off >>= 1) pr += __shfl_xor(pr, off);
      if (n == 0) S.sc.bcv[r] = pr;
    }
    __syncthreads();

    // P3: dt = softplus(dt_r @ W_dt + b_dt); y = (dt*bc + D)*x_c*silu(z) -> xc
    {
      const float* wp = Wdt + t;
      const float2* p0 = reinterpret_cast<const float2*>(&S.sc.proj[0][0]);
      const float2* p1 = reinterpret_cast<const float2*>(&S.sc.proj[1][0]);
      float a0 = bdtv, a1 = bdtv;
#pragma unroll
      for (int q2 = 0; q2 < 16; ++q2) {
        float w0 = wp[0], w1 = wp[1024];
        wp += 2048;
        float2 q0 = p0[q2], q1 = p1[q2];
        a0 += q0.x * w0 + q0.y * w1;
        a1 += q1.x * w0 + q1.y * w1;
      }
      float accs[2] = {a0, a1};
#pragma unroll
      for (int r = 0; r < 2; ++r) {
        float v = accs[r];
        float sp = fmaxf(v, 0.f) + log1pf(__expf(-fabsf(v)));
        S.sc.xc[r][t] = (sp * S.sc.bcv[r] + dpar) * xcr[r] * zsr[r];
      }
    }
    __syncthreads();

    // Pts: ts = y @ Wts + bts. Wave w (0..13) owns output c=w; WtsT from L1-hot global.
    {
      int w = t >> 6, l = t & 63;
      if (w < 14) {
        const float* wtp = WtsT_ws + w * 1024 + l;
        float a0 = 0, a1 = 0;
#pragma unroll 4
        for (int i = 0; i < 16; ++i) {
          float wt = wtp[i * 64];
          a0 += S.sc.xc[0][l + i * 64] * wt;
          a1 += S.sc.xc[1][l + i * 64] * wt;
        }
#pragma unroll
        for (int off = 32; off; off >>= 1) {
          a0 += __shfl_xor(a0, off); a1 += __shfl_xor(a1, off);
        }
        if (l == 0) {
          float b = bts_ws[w];
          float v0 = a0 + b, v1 = a1 + b;
          S.sc.ts[0][w] = v0; S.sc.ts[1][w] = v1;
          size_t i0 = ((size_t)(r0 + 0) * 64 + step) * 7;
          size_t i1 = ((size_t)(r0 + 1) * 64 + step) * 7;
          if (w < 7) { out[i0 + w] = v0; out[i1 + w] = v1; }
          else { out[458752 + i0 + (w - 7)] = v0; out[458752 + i1 + (w - 7)] = v1; }
        }
      }
    }
    __syncthreads();

    // P7: comb = [trend,seas] @ W_fin + b_fin, write out + feedback
    if (t < 14) {
      int r = t / 7, c = t - (t / 7) * 7;
      float s = b_fin[c];
#pragma unroll
      for (int i = 0; i < 14; ++i) s += S.sc.ts[r][i] * W_fin[i * 7 + c];
      S.sc.combs[r][c] = s;
      out[917504 + ((size_t)(r0 + r) * 64 + step) * 7 + c] = s;
    }
    __syncthreads();
  }
}

extern "C" void kernel_launch(void* const* d_in, const int* in_sizes, int n_in,
                              void* d_out, int out_size, void* d_ws, size_t ws_size,
                              hipStream_t stream) {
  const float* tc       = (const float*)d_in[0];
  const float* cc       = (const float*)d_in[1];
  const float* initv    = (const float*)d_in[2];
  const float* W_cf     = (const float*)d_in[3];
  const float* b_cf     = (const float*)d_in[4];
  const float* ln_g     = (const float*)d_in[5];
  const float* ln_b     = (const float*)d_in[6];
  const float* W_feat   = (const float*)d_in[7];
  const float* b_feat   = (const float*)d_in[8];
  const float* W_inproj = (const float*)d_in[9];
  const float* b_inproj = (const float*)d_in[10];
  const float* conv_w   = (const float*)d_in[11];
  const float* conv_b   = (const float*)d_in[12];
  const float* W_xproj  = (const float*)d_in[13];
  const float* W_dt     = (const float*)d_in[14];
  const float* b_dt     = (const float*)d_in[15];
  const float* D_param  = (const float*)d_in[16];
  const float* W_out    = (const float*)d_in[17];
  const float* b_out    = (const float*)d_in[18];
  const float* W_tr     = (const float*)d_in[19];
  const float* b_tr     = (const float*)d_in[20];
  const float* W_se     = (const float*)d_in[21];
  const float* b_se     = (const float*)d_in[22];
  const float* W_fin    = (const float*)d_in[23];
  const float* b_fin    = (const float*)d_in[24];

  float* ws = (float*)d_ws;   // needs 114744 B

  hipLaunchKernelGGL(k_fold, dim3(13), dim3(256), 0, stream,
                     W_feat, W_inproj, W_out, W_tr, W_se, b_out, b_tr, b_se, ws);
  hipLaunchKernelGGL(k_scan, dim3(512), dim3(1024), 0, stream,
                     tc, cc, initv, W_cf, b_cf, ln_g, ln_b, W_feat, b_feat,
                     W_inproj, b_inproj, conv_w, conv_b, W_xproj, W_dt, b_dt,
                     D_param, W_fin, b_fin, ws, (float*)d_out);
}

// Round 8
// 2718.685 us; speedup vs baseline: 1.1305x; 1.1305x over previous
//
#include <hip/hip_runtime.h>

// ws layout (fp32):
//   Wcx  [7][2048]  @ float offset 0      (57344 B)  xz-feedback fold
//   WtsT [14][1024] @ float offset 14336  (57344 B)  (W_out @ [W_tr|W_se])^T
//   bts  [14]       @ float offset 28672  (56 B)
// total 114744 B

// ---------------- one-time weight folds ----------------
__global__ __launch_bounds__(256) void k_fold(
    const float* __restrict__ W_feat, const float* __restrict__ W_inproj,
    const float* __restrict__ Wout, const float* __restrict__ Wtr,
    const float* __restrict__ Wse, const float* __restrict__ b_out,
    const float* __restrict__ b_tr, const float* __restrict__ b_se,
    float* __restrict__ ws) {
  float* Wcx  = ws;
  float* WtsT = ws + 14336;
  float* bts  = ws + 28672;
  const int b = blockIdx.x, t = threadIdx.x;
  if (b < 8) {
    int j = b * 256 + t;
    float acc[7] = {0, 0, 0, 0, 0, 0, 0};
    for (int k = 0; k < 512; ++k) {
      float wi = W_inproj[(size_t)k * 2048 + j];
#pragma unroll
      for (int i = 0; i < 7; ++i) acc[i] += W_feat[(size_t)(512 + i) * 512 + k] * wi;
    }
#pragma unroll
    for (int i = 0; i < 7; ++i) Wcx[i * 2048 + j] = acc[i];
  } else if (b < 12) {
    int k = (b - 8) * 256 + t;
    float acc[14];
#pragma unroll
    for (int c = 0; c < 14; ++c) acc[c] = 0.f;
    const float* wo = Wout + (size_t)k * 512;
    for (int o = 0; o < 512; ++o) {
      float w = wo[o];
      const float* tr = Wtr + o * 7;
      const float* se = Wse + o * 7;
#pragma unroll
      for (int c = 0; c < 7; ++c) { acc[c] += w * tr[c]; acc[7 + c] += w * se[c]; }
    }
#pragma unroll
    for (int c = 0; c < 14; ++c) WtsT[c * 1024 + k] = acc[c];
  } else {
    if (t < 14) {
      int c = (t < 7) ? t : t - 7;
      const float* W = (t < 7) ? Wtr : Wse;
      float s = (t < 7) ? b_tr[t] : b_se[t - 7];
      for (int o = 0; o < 512; ++o) s += b_out[o] * W[o * 7 + c];
      bts[t] = s;
    }
  }
}

// ---------------- persistent scan: 512 blocks x 1024 thr, 2 rows/block ------
struct Pro {                       // prologue-only
  float hb[2][512];                // 4K
  float hin[2][512];               // 4K
  float hpart[2][2][512];          // 8K
};
struct Sc {                        // scan-phase
  float xc[2][1024];               // 8K
  float part2[4][2][160];          // 5K
  float proj[2][32];               // 256B
  float combs[2][8];
  float bcv[2];
  float ts[2][16];
};
union SMem { Pro pro; Sc sc; };

__global__ __launch_bounds__(1024, 2) void k_scan(
    const float* __restrict__ tc, const float* __restrict__ cc,
    const float* __restrict__ initv,
    const float* __restrict__ W_cf, const float* __restrict__ b_cf,
    const float* __restrict__ ln_g, const float* __restrict__ ln_b,
    const float* __restrict__ W_feat, const float* __restrict__ b_feat,
    const float* __restrict__ W_inproj, const float* __restrict__ b_inproj,
    const float* __restrict__ conv_w, const float* __restrict__ conv_b,
    const float* __restrict__ Wxp,
    const float* __restrict__ Wdt, const float* __restrict__ b_dt,
    const float* __restrict__ D_param,
    const float* __restrict__ W_fin, const float* __restrict__ b_fin,
    const float* __restrict__ ws, float* __restrict__ out) {
  __shared__ SMem S;
  __shared__ float WtsT[14][1024];   // persistent 56K
  const float* Wcx_ws = ws;
  const float* bts_ws = ws + 28672;
  const int t = threadIdx.x;          // 0..1023
  const int r0 = blockIdx.x * 2;
  const int o9 = t & 511;
  const int kc9 = t >> 9;

  // stage WtsT (written by k_fold) into LDS
  for (int idx = t; idx < 14336; idx += 1024)
    WtsT[idx >> 10][idx & 1023] = ws[14336 + idx];

  // ---- h = relu([tc,cc] @ W_cf + b_cf) ----
  {
    const float* src = ((kc9 == 0) ? tc : cc) + (size_t)r0 * 512;
    const float* wp = W_cf + (size_t)(kc9 * 512) * 512 + o9;
    float a0 = 0, a1 = 0;
    for (int k = 0; k < 512; ++k) {
      float w = wp[0]; wp += 512;
      a0 += src[k] * w; a1 += src[512 + k] * w;
    }
    S.pro.hpart[kc9][0][o9] = a0; S.pro.hpart[kc9][1][o9] = a1;
  }
  __syncthreads();
  S.pro.hb[kc9][o9] = fmaxf(S.pro.hpart[0][kc9][o9] + S.pro.hpart[1][kc9][o9] + b_cf[o9], 0.f);
  __syncthreads();
  // ---- LayerNorm ----
  if (t < 128) {
    int w = t >> 6, lane = t & 63;
    float s = 0.f, s2 = 0.f;
    for (int j = lane; j < 512; j += 64) { float v = S.pro.hb[w][j]; s += v; s2 += v * v; }
#pragma unroll
    for (int off = 32; off; off >>= 1) { s += __shfl_xor(s, off); s2 += __shfl_xor(s2, off); }
    float mu = s * (1.f / 512.f);
    float var = s2 * (1.f / 512.f) - mu * mu;
    float inv = rsqrtf(var + 1e-5f);
    for (int j = lane; j < 512; j += 64)
      S.pro.hb[w][j] = (S.pro.hb[w][j] - mu) * inv * ln_g[j] + ln_b[j];
  }
  __syncthreads();
  // ---- hin = fused @ W_feat[:512] + b_feat ----
  {
    int k0 = kc9 * 256;
    const float* wp = W_feat + (size_t)k0 * 512 + o9;
    float a0 = 0, a1 = 0;
    for (int k = k0; k < k0 + 256; ++k) {
      float w = wp[0]; wp += 512;
      a0 += S.pro.hb[0][k] * w; a1 += S.pro.hb[1][k] * w;
    }
    S.pro.hpart[kc9][0][o9] = a0; S.pro.hpart[kc9][1][o9] = a1;
  }
  __syncthreads();
  S.pro.hin[kc9][o9] = S.pro.hpart[0][kc9][o9] + S.pro.hpart[1][kc9][o9] + b_feat[o9];
  __syncthreads();

  // ---- xz_base cols t (x) and 1024+t (z) into registers ----
  float xzbx[2], xzbz[2];
#pragma unroll
  for (int half = 0; half < 2; ++half) {
    int col = t + half * 1024;
    const float* wp = W_inproj + col;
    float a0 = 0, a1 = 0;
    for (int k = 0; k < 512; ++k) {
      float wi = wp[0]; wp += 2048;
      a0 += S.pro.hin[0][k] * wi; a1 += S.pro.hin[1][k] * wi;
    }
    float bi = b_inproj[col];
    if (half == 0) { xzbx[0] = a0 + bi; xzbx[1] = a1 + bi; }
    else           { xzbz[0] = a0 + bi; xzbz[1] = a1 + bi; }
  }

  // ---- step-invariant per-thread constants ----
  float wcxx[7], wcxz[7];
#pragma unroll
  for (int i = 0; i < 7; ++i) {
    wcxx[i] = Wcx_ws[i * 2048 + t];
    wcxz[i] = Wcx_ws[i * 2048 + 1024 + t];
  }
  const float cw3  = conv_w[t * 4 + 3];
  const float cbv  = conv_b[t];
  const float dpar = D_param[t];
  const float bdtv = b_dt[t];

  if (t < 14) S.sc.combs[t / 7][t % 7] = initv[(r0 + t / 7) * 7 + (t % 7)];
  __syncthreads();

  // ================= 64 sequential decode steps =================
  float zsr[2], xcr[2];
  for (int step = 0; step < 64; ++step) {
    // P1
#pragma unroll
    for (int r = 0; r < 2; ++r) {
      float v = xzbx[r], u = xzbz[r];
#pragma unroll
      for (int i = 0; i < 7; ++i) {
        float cb_ = S.sc.combs[r][i];
        v += cb_ * wcxx[i];
        u += cb_ * wcxz[i];
      }
      v = v * cw3 + cbv;
      float sv = v / (1.f + __expf(-v));
      xcr[r] = sv;
      S.sc.xc[r][t] = sv;
      zsr[r] = u / (1.f + __expf(-u));
    }
    __syncthreads();

    // P2: part2 = x_c @ W_xproj, K=1024 split in 4 (640 threads)
    if (t < 640) {
      int kc = t / 160, p = t - kc * 160;
      const float* wp = Wxp + (size_t)(kc * 256) * 160 + p;
      const float2* x0 = reinterpret_cast<const float2*>(&S.sc.xc[0][kc * 256]);
      const float2* x1 = reinterpret_cast<const float2*>(&S.sc.xc[1][kc * 256]);
      float a0 = 0, a1 = 0;
#pragma unroll 4
      for (int i = 0; i < 128; ++i) {
        float w0 = wp[0], w1 = wp[160];
        wp += 320;
        float2 v0 = x0[i], v1 = x1[i];
        a0 += v0.x * w0 + v0.y * w1;
        a1 += v1.x * w0 + v1.y * w1;
      }
      S.sc.part2[kc][0][p] = a0; S.sc.part2[kc][1][p] = a1;
    }
    __syncthreads();

    // reduce dt_r + bc = <Bm,Cm>
    if (t < 64) {
      int r = t >> 5, p = t & 31;
      S.sc.proj[r][p] = S.sc.part2[0][r][p] + S.sc.part2[1][r][p] +
                        S.sc.part2[2][r][p] + S.sc.part2[3][r][p];
    } else if (t >= 256 && t < 384) {
      int r = (t - 256) >> 6, n = t & 63;
      float bm = S.sc.part2[0][r][32 + n] + S.sc.part2[1][r][32 + n] +
                 S.sc.part2[2][r][32 + n] + S.sc.part2[3][r][32 + n];
      float cm = S.sc.part2[0][r][96 + n] + S.sc.part2[1][r][96 + n] +
                 S.sc.part2[2][r][96 + n] + S.sc.part2[3][r][96 + n];
      float pr = bm * cm;
#pragma unroll
      for (int off = 32; off; off >>= 1) pr += __shfl_xor(pr, off);
      if (n == 0) S.sc.bcv[r] = pr;
    }
    __syncthreads();

    // P3
    {
      const float* wp = Wdt + t;
      const float2* p0 = reinterpret_cast<const float2*>(&S.sc.proj[0][0]);
      const float2* p1 = reinterpret_cast<const float2*>(&S.sc.proj[1][0]);
      float a0 = bdtv, a1 = bdtv;
#pragma unroll
      for (int q2 = 0; q2 < 16; ++q2) {
        float w0 = wp[0], w1 = wp[1024];
        wp += 2048;
        float2 q0 = p0[q2], q1 = p1[q2];
        a0 += q0.x * w0 + q0.y * w1;
        a1 += q1.x * w0 + q1.y * w1;
      }
      float accs[2] = {a0, a1};
#pragma unroll
      for (int r = 0; r < 2; ++r) {
        float v = accs[r];
        float sp = fmaxf(v, 0.f) + log1pf(__expf(-fabsf(v)));
        S.sc.xc[r][t] = (sp * S.sc.bcv[r] + dpar) * xcr[r] * zsr[r];
      }
    }
    __syncthreads();

    // Pts: ts = y @ Wts + bts (WtsT in LDS)
    {
      int w = t >> 6, l = t & 63;
      if (w < 14) {
        float a0 = 0, a1 = 0;
#pragma unroll 4
        for (int i = 0; i < 16; ++i) {
          float wt = WtsT[w][l + i * 64];
          a0 += S.sc.xc[0][l + i * 64] * wt;
          a1 += S.sc.xc[1][l + i * 64] * wt;
        }
#pragma unroll
        for (int off = 32; off; off >>= 1) {
          a0 += __shfl_xor(a0, off); a1 += __shfl_xor(a1, off);
        }
        if (l == 0) {
          float b = bts_ws[w];
          float v0 = a0 + b, v1 = a1 + b;
          S.sc.ts[0][w] = v0; S.sc.ts[1][w] = v1;
          size_t i0 = ((size_t)(r0 + 0) * 64 + step) * 7;
          size_t i1 = ((size_t)(r0 + 1) * 64 + step) * 7;
          if (w < 7) { out[i0 + w] = v0; out[i1 + w] = v1; }
          else { out[458752 + i0 + (w - 7)] = v0; out[458752 + i1 + (w - 7)] = v1; }
        }
      }
    }
    __syncthreads();

    // P7: comb feedback
    if (t < 14) {
      int r = t / 7, c = t - (t / 7) * 7;
      float s = b_fin[c];
#pragma unroll
      for (int i = 0; i < 14; ++i) s += S.sc.ts[r][i] * W_fin[i * 7 + c];
      S.sc.combs[r][c] = s;
      out[917504 + ((size_t)(r0 + r) * 64 + step) * 7 + c] = s;
    }
    __syncthreads();
  }
}

extern "C" void kernel_launch(void* const* d_in, const int* in_sizes, int n_in,
                              void* d_out, int out_size, void* d_ws, size_t ws_size,
                              hipStream_t stream) {
  const float* tc       = (const float*)d_in[0];
  const float* cc       = (const float*)d_in[1];
  const float* initv    = (const float*)d_in[2];
  const float* W_cf     = (const float*)d_in[3];
  const float* b_cf     = (const float*)d_in[4];
  const float* ln_g     = (const float*)d_in[5];
  const float* ln_b     = (const float*)d_in[6];
  const float* W_feat   = (const float*)d_in[7];
  const float* b_feat   = (const float*)d_in[8];
  const float* W_inproj = (const float*)d_in[9];
  const float* b_inproj = (const float*)d_in[10];
  const float* conv_w   = (const float*)d_in[11];
  const float* conv_b   = (const float*)d_in[12];
  const float* W_xproj  = (const float*)d_in[13];
  const float* W_dt     = (const float*)d_in[14];
  const float* b_dt     = (const float*)d_in[15];
  const float* D_param  = (const float*)d_in[16];
  const float* W_out    = (const float*)d_in[17];
  const float* b_out    = (const float*)d_in[18];
  const float* W_tr     = (const float*)d_in[19];
  const float* b_tr     = (const float*)d_in[20];
  const float* W_se     = (const float*)d_in[21];
  const float* b_se     = (const float*)d_in[22];
  const float* W_fin    = (const float*)d_in[23];
  const float* b_fin    = (const float*)d_in[24];

  float* ws = (float*)d_ws;   // needs 114744 B

  hipLaunchKernelGGL(k_fold, dim3(13), dim3(256), 0, stream,
                     W_feat, W_inproj, W_out, W_tr, W_se, b_out, b_tr, b_se, ws);
  hipLaunchKernelGGL(k_scan, dim3(512), dim3(1024), 0, stream,
                     tc, cc, initv, W_cf, b_cf, ln_g, ln_b, W_feat, b_feat,
                     W_inproj, b_inproj, conv_w, conv_b, W_xproj, W_dt, b_dt,
                     D_param, W_fin, b_fin, ws, (float*)d_out);
}

// Round 9
// 2553.998 us; speedup vs baseline: 1.2034x; 1.0645x over previous
//
#include <hip/hip_runtime.h>

// ws layout (float offsets):
//   Wcx  [7][2048]        @ 0       xz-feedback fold
//   WtsT [14][1024]       @ 14336   (W_out @ [W_tr|W_se])^T
//   bts  [14]             @ 28672
//   WxpR [8][80][32][2][4]@ 28928   Wxp retiled: thread-contiguous 1KB streams
//   WdtR [1024][32]       @ 192768  Wdt transposed: 128B/thread contiguous
// total (192768+32768)*4 = 902144 B
#define WS_WCX  0
#define WS_WTST 14336
#define WS_BTS  28672
#define WS_WXPR 28928
#define WS_WDTR 192768

// ---------------- one-time weight folds + retiles ----------------
__global__ __launch_bounds__(256) void k_fold(
    const float* __restrict__ W_feat, const float* __restrict__ W_inproj,
    const float* __restrict__ Wout, const float* __restrict__ Wtr,
    const float* __restrict__ Wse, const float* __restrict__ b_out,
    const float* __restrict__ b_tr, const float* __restrict__ b_se,
    const float* __restrict__ Wxp, const float* __restrict__ Wdt,
    float* __restrict__ ws) {
  const int b = blockIdx.x, t = threadIdx.x;
  if (b < 8) {                       // Wcx[i][j] = sum_k W_feat[512+i][k] W_inproj[k][j]
    int j = b * 256 + t;
    float acc[7] = {0, 0, 0, 0, 0, 0, 0};
    for (int k = 0; k < 512; ++k) {
      float wi = W_inproj[(size_t)k * 2048 + j];
#pragma unroll
      for (int i = 0; i < 7; ++i) acc[i] += W_feat[(size_t)(512 + i) * 512 + k] * wi;
    }
#pragma unroll
    for (int i = 0; i < 7; ++i) ws[WS_WCX + i * 2048 + j] = acc[i];
  } else if (b < 12) {               // WtsT[c][k] = sum_o Wout[k][o]*[Wtr|Wse][o][c]
    int k = (b - 8) * 256 + t;
    float acc[14];
#pragma unroll
    for (int c = 0; c < 14; ++c) acc[c] = 0.f;
    const float* wo = Wout + (size_t)k * 512;
    for (int o = 0; o < 512; ++o) {
      float w = wo[o];
      const float* tr = Wtr + o * 7;
      const float* se = Wse + o * 7;
#pragma unroll
      for (int c = 0; c < 7; ++c) { acc[c] += w * tr[c]; acc[7 + c] += w * se[c]; }
    }
#pragma unroll
    for (int c = 0; c < 14; ++c) ws[WS_WTST + c * 1024 + k] = acc[c];
  } else if (b == 12) {              // bts
    if (t < 14) {
      int c = (t < 7) ? t : t - 7;
      const float* W = (t < 7) ? Wtr : Wse;
      float s = (t < 7) ? b_tr[t] : b_se[t - 7];
      for (int o = 0; o < 512; ++o) s += b_out[o] * W[o * 7 + c];
      ws[WS_BTS + t] = s;
    }
  } else if (b < 653) {              // WxpR
    int idx = (b - 13) * 256 + t;    // [0, 163840)
    int kin = idx & 3, pc = (idx >> 2) & 1, k4 = (idx >> 3) & 31;
    int g = idx >> 8, kc = g / 80, pp = g - kc * 80;
    int k = kc * 128 + k4 * 4 + kin, p = pp * 2 + pc;
    ws[WS_WXPR + idx] = Wxp[(size_t)k * 160 + p];
  } else {                           // WdtR[o][q] = Wdt[q][o]
    int idx = (b - 653) * 256 + t;   // [0, 32768)
    int o = idx >> 5, q = idx & 31;
    ws[WS_WDTR + idx] = Wdt[(size_t)q * 1024 + o];
  }
}

// ---------------- persistent scan: 256 blocks x 1024 thr, 4 rows/block ------
struct Pro {                        // prologue-only
  float x2[4][1024];                // 16K
  float hb[4][512];                 // 8K
  float hin[4][512];                // 8K
  float hpart[2][4][512];           // 16K
};
struct Sc {                         // scan-phase
  float xc[4][1024];                // 16K
  float part2[8][4][160];           // 20K
  float proj[4][32];                // 512B
  float combs[4][8];
  float bcv[4];
  float ts[4][16];
};
union SMem { Pro pro; Sc sc; };

__global__ __launch_bounds__(1024) void k_scan(
    const float* __restrict__ tc, const float* __restrict__ cc,
    const float* __restrict__ initv,
    const float* __restrict__ W_cf, const float* __restrict__ b_cf,
    const float* __restrict__ ln_g, const float* __restrict__ ln_b,
    const float* __restrict__ W_feat, const float* __restrict__ b_feat,
    const float* __restrict__ W_inproj, const float* __restrict__ b_inproj,
    const float* __restrict__ conv_w, const float* __restrict__ conv_b,
    const float* __restrict__ b_dt, const float* __restrict__ D_param,
    const float* __restrict__ W_fin, const float* __restrict__ b_fin,
    const float* __restrict__ ws, float* __restrict__ out) {
  __shared__ SMem S;
  const int t = threadIdx.x;          // 0..1023
  const int r0 = blockIdx.x * 4;
  const int o9 = t & 511;
  const int kc9 = t >> 9;

  // ================= prologue =================
  for (int idx = t; idx < 4096; idx += 1024) {
    int r = idx >> 10, k = idx & 1023;
    S.pro.x2[r][k] = (k < 512) ? tc[(size_t)(r0 + r) * 512 + k]
                               : cc[(size_t)(r0 + r) * 512 + (k - 512)];
  }
  __syncthreads();
  // h = relu([tc,cc] @ W_cf + b_cf), K split 2x512
  {
    const float* wp = W_cf + (size_t)(kc9 * 512) * 512 + o9;
    int k0 = kc9 * 512;
    float a0 = 0, a1 = 0, a2 = 0, a3 = 0;
    for (int k = k0; k < k0 + 512; ++k) {
      float w = wp[0]; wp += 512;
      a0 += S.pro.x2[0][k] * w; a1 += S.pro.x2[1][k] * w;
      a2 += S.pro.x2[2][k] * w; a3 += S.pro.x2[3][k] * w;
    }
    S.pro.hpart[kc9][0][o9] = a0; S.pro.hpart[kc9][1][o9] = a1;
    S.pro.hpart[kc9][2][o9] = a2; S.pro.hpart[kc9][3][o9] = a3;
  }
  __syncthreads();
  {
    float b = b_cf[o9];
#pragma unroll
    for (int rr = 0; rr < 2; ++rr) {
      int r = kc9 * 2 + rr;
      S.pro.hb[r][o9] = fmaxf(S.pro.hpart[0][r][o9] + S.pro.hpart[1][r][o9] + b, 0.f);
    }
  }
  __syncthreads();
  // LayerNorm
  if (t < 256) {
    int w = t >> 6, lane = t & 63;
    float s = 0.f, s2 = 0.f;
    for (int j = lane; j < 512; j += 64) { float v = S.pro.hb[w][j]; s += v; s2 += v * v; }
#pragma unroll
    for (int off = 32; off; off >>= 1) { s += __shfl_xor(s, off); s2 += __shfl_xor(s2, off); }
    float mu = s * (1.f / 512.f);
    float var = s2 * (1.f / 512.f) - mu * mu;
    float inv = rsqrtf(var + 1e-5f);
    for (int j = lane; j < 512; j += 64)
      S.pro.hb[w][j] = (S.pro.hb[w][j] - mu) * inv * ln_g[j] + ln_b[j];
  }
  __syncthreads();
  // hin = fused @ W_feat[:512] + b_feat, K split 2x256
  {
    int k0 = kc9 * 256;
    const float* wp = W_feat + (size_t)k0 * 512 + o9;
    float a0 = 0, a1 = 0, a2 = 0, a3 = 0;
    for (int k = k0; k < k0 + 256; ++k) {
      float w = wp[0]; wp += 512;
      a0 += S.pro.hb[0][k] * w; a1 += S.pro.hb[1][k] * w;
      a2 += S.pro.hb[2][k] * w; a3 += S.pro.hb[3][k] * w;
    }
    S.pro.hpart[kc9][0][o9] = a0; S.pro.hpart[kc9][1][o9] = a1;
    S.pro.hpart[kc9][2][o9] = a2; S.pro.hpart[kc9][3][o9] = a3;
  }
  __syncthreads();
  {
    float b = b_feat[o9];
#pragma unroll
    for (int rr = 0; rr < 2; ++rr) {
      int r = kc9 * 2 + rr;
      S.pro.hin[r][o9] = S.pro.hpart[0][r][o9] + S.pro.hpart[1][r][o9] + b;
    }
  }
  __syncthreads();

  // xz_base: thread t owns cols t (x half) and 1024+t (z half), 4 rows
  float xzbx[4], xzbz[4];
#pragma unroll
  for (int half = 0; half < 2; ++half) {
    int col = t + half * 1024;
    const float* wp = W_inproj + col;
    float a0 = 0, a1 = 0, a2 = 0, a3 = 0;
    for (int k = 0; k < 512; ++k) {
      float wi = wp[0]; wp += 2048;
      a0 += S.pro.hin[0][k] * wi; a1 += S.pro.hin[1][k] * wi;
      a2 += S.pro.hin[2][k] * wi; a3 += S.pro.hin[3][k] * wi;
    }
    float bi = b_inproj[col];
    if (half == 0) { xzbx[0] = a0 + bi; xzbx[1] = a1 + bi; xzbx[2] = a2 + bi; xzbx[3] = a3 + bi; }
    else           { xzbz[0] = a0 + bi; xzbz[1] = a1 + bi; xzbz[2] = a2 + bi; xzbz[3] = a3 + bi; }
  }

  // ---- step-invariant per-thread constants ----
  float wcxx[7], wcxz[7];
#pragma unroll
  for (int i = 0; i < 7; ++i) {
    wcxx[i] = ws[WS_WCX + i * 2048 + t];
    wcxz[i] = ws[WS_WCX + i * 2048 + 1024 + t];
  }
  const float cw3  = conv_w[t * 4 + 3];
  const float cbv  = conv_b[t];
  const float dpar = D_param[t];
  const float bdtv = b_dt[t];
  // Pts weights in registers (wave w = t>>6 owns output c=w)
  const int wv = t >> 6, ln = t & 63;
  float wts[16], btsw = 0.f;
  if (wv < 14) {
#pragma unroll
    for (int i = 0; i < 16; ++i) wts[i] = ws[WS_WTST + wv * 1024 + ln + i * 64];
    btsw = ws[WS_BTS + wv];
  } else {
#pragma unroll
    for (int i = 0; i < 16; ++i) wts[i] = 0.f;
  }

  if (t < 28) S.sc.combs[t / 7][t % 7] = initv[(r0 + t / 7) * 7 + (t % 7)];
  __syncthreads();

  // ================= 64 sequential decode steps =================
  float zsr[4], xcr[4];
  for (int step = 0; step < 64; ++step) {
    // P1: xz = xz_base + comb @ Wcx; x_c=silu(conv) -> LDS+reg; silu(z) -> reg
#pragma unroll
    for (int r = 0; r < 4; ++r) {
      float v = xzbx[r], u = xzbz[r];
#pragma unroll
      for (int i = 0; i < 7; ++i) {
        float cb_ = S.sc.combs[r][i];
        v += cb_ * wcxx[i];
        u += cb_ * wcxz[i];
      }
      v = v * cw3 + cbv;
      float sv = v / (1.f + __expf(-v));
      xcr[r] = sv;
      S.sc.xc[r][t] = sv;
      zsr[r] = u / (1.f + __expf(-u));
    }
    __syncthreads();

    // P2: x_c @ Wxp. 640 thr = 8 K-chunks(128) x 80 col-pairs; 2 out x 4 rows tiles.
    if (t < 640) {
      int kc = t / 80, pp = t - kc * 80;
      const float4* wp4 = reinterpret_cast<const float4*>(ws + WS_WXPR + (size_t)(kc * 80 + pp) * 256);
      int kb = kc * 128;
      const float4* x0 = reinterpret_cast<const float4*>(&S.sc.xc[0][kb]);
      const float4* x1 = reinterpret_cast<const float4*>(&S.sc.xc[1][kb]);
      const float4* x2_ = reinterpret_cast<const float4*>(&S.sc.xc[2][kb]);
      const float4* x3 = reinterpret_cast<const float4*>(&S.sc.xc[3][kb]);
      float a00 = 0, a01 = 0, a02 = 0, a03 = 0;
      float a10 = 0, a11 = 0, a12 = 0, a13 = 0;
#pragma unroll 4
      for (int k4 = 0; k4 < 32; ++k4) {
        float4 wA = wp4[2 * k4], wB = wp4[2 * k4 + 1];
        float4 v0 = x0[k4], v1 = x1[k4], v2 = x2_[k4], v3 = x3[k4];
        a00 += wA.x * v0.x + wA.y * v0.y + wA.z * v0.z + wA.w * v0.w;
        a01 += wA.x * v1.x + wA.y * v1.y + wA.z * v1.z + wA.w * v1.w;
        a02 += wA.x * v2.x + wA.y * v2.y + wA.z * v2.z + wA.w * v2.w;
        a03 += wA.x * v3.x + wA.y * v3.y + wA.z * v3.z + wA.w * v3.w;
        a10 += wB.x * v0.x + wB.y * v0.y + wB.z * v0.z + wB.w * v0.w;
        a11 += wB.x * v1.x + wB.y * v1.y + wB.z * v1.z + wB.w * v1.w;
        a12 += wB.x * v2.x + wB.y * v2.y + wB.z * v2.z + wB.w * v2.w;
        a13 += wB.x * v3.x + wB.y * v3.y + wB.z * v3.z + wB.w * v3.w;
      }
      int p0 = pp * 2, p1 = p0 + 1;
      S.sc.part2[kc][0][p0] = a00; S.sc.part2[kc][1][p0] = a01;
      S.sc.part2[kc][2][p0] = a02; S.sc.part2[kc][3][p0] = a03;
      S.sc.part2[kc][0][p1] = a10; S.sc.part2[kc][1][p1] = a11;
      S.sc.part2[kc][2][p1] = a12; S.sc.part2[kc][3][p1] = a13;
    }
    __syncthreads();

    // reduce dt_r (proj[:, :32]) + bc = <Bm,Cm>
    if (t < 128) {
      int r = t >> 5, p = t & 31;
      float s = 0.f;
#pragma unroll
      for (int c = 0; c < 8; ++c) s += S.sc.part2[c][r][p];
      S.sc.proj[r][p] = s;
    } else if (t >= 256 && t < 512) {
      int r = (t - 256) >> 6, n = t & 63;
      float bm = 0.f, cm = 0.f;
#pragma unroll
      for (int c = 0; c < 8; ++c) {
        bm += S.sc.part2[c][r][32 + n];
        cm += S.sc.part2[c][r][96 + n];
      }
      float pr = bm * cm;
#pragma unroll
      for (int off = 32; off; off >>= 1) pr += __shfl_xor(pr, off);
      if (n == 0) S.sc.bcv[r] = pr;
    }
    __syncthreads();

    // P3: dt = softplus(dt_r @ W_dt + b_dt); y = (dt*bc + D)*x_c*silu(z) -> xc
    {
      const float4* wd4 = reinterpret_cast<const float4*>(ws + WS_WDTR + (size_t)t * 32);
      const float4* q0 = reinterpret_cast<const float4*>(&S.sc.proj[0][0]);
      const float4* q1 = reinterpret_cast<const float4*>(&S.sc.proj[1][0]);
      const float4* q2 = reinterpret_cast<const float4*>(&S.sc.proj[2][0]);
      const float4* q3 = reinterpret_cast<const float4*>(&S.sc.proj[3][0]);
      float a0 = bdtv, a1 = bdtv, a2 = bdtv, a3 = bdtv;
#pragma unroll
      for (int q4 = 0; q4 < 8; ++q4) {
        float4 w = wd4[q4];
        float4 p0 = q0[q4], p1 = q1[q4], p2 = q2[q4], p3 = q3[q4];
        a0 += w.x * p0.x + w.y * p0.y + w.z * p0.z + w.w * p0.w;
        a1 += w.x * p1.x + w.y * p1.y + w.z * p1.z + w.w * p1.w;
        a2 += w.x * p2.x + w.y * p2.y + w.z * p2.z + w.w * p2.w;
        a3 += w.x * p3.x + w.y * p3.y + w.z * p3.z + w.w * p3.w;
      }
      float accs[4] = {a0, a1, a2, a3};
#pragma unroll
      for (int r = 0; r < 4; ++r) {
        float v = accs[r];
        float sp = fmaxf(v, 0.f) + log1pf(__expf(-fabsf(v)));
        S.sc.xc[r][t] = (sp * S.sc.bcv[r] + dpar) * xcr[r] * zsr[r];
      }
    }
    __syncthreads();

    // Pts: ts = y @ Wts + bts (weights in registers)
    if (wv < 14) {
      float a0 = 0, a1 = 0, a2 = 0, a3 = 0;
#pragma unroll
      for (int i = 0; i < 16; ++i) {
        int k = ln + i * 64;
        float wt = wts[i];
        a0 += S.sc.xc[0][k] * wt; a1 += S.sc.xc[1][k] * wt;
        a2 += S.sc.xc[2][k] * wt; a3 += S.sc.xc[3][k] * wt;
      }
#pragma unroll
      for (int off = 32; off; off >>= 1) {
        a0 += __shfl_xor(a0, off); a1 += __shfl_xor(a1, off);
        a2 += __shfl_xor(a2, off); a3 += __shfl_xor(a3, off);
      }
      if (ln == 0) {
        float v0 = a0 + btsw, v1 = a1 + btsw, v2 = a2 + btsw, v3 = a3 + btsw;
        S.sc.ts[0][wv] = v0; S.sc.ts[1][wv] = v1;
        S.sc.ts[2][wv] = v2; S.sc.ts[3][wv] = v3;
        float vals[4] = {v0, v1, v2, v3};
#pragma unroll
        for (int r = 0; r < 4; ++r) {
          size_t idx = ((size_t)(r0 + r) * 64 + step) * 7;
          if (wv < 7) out[idx + wv] = vals[r];
          else out[458752 + idx + (wv - 7)] = vals[r];
        }
      }
    }
    __syncthreads();

    // P7: comb = [trend,seas] @ W_fin + b_fin, write out + feedback
    if (t < 28) {
      int r = t / 7, c = t - (t / 7) * 7;
      float s = b_fin[c];
#pragma unroll
      for (int i = 0; i < 14; ++i) s += S.sc.ts[r][i] * W_fin[i * 7 + c];
      S.sc.combs[r][c] = s;
      out[917504 + ((size_t)(r0 + r) * 64 + step) * 7 + c] = s;
    }
    __syncthreads();
  }
}

extern "C" void kernel_launch(void* const* d_in, const int* in_sizes, int n_in,
                              void* d_out, int out_size, void* d_ws, size_t ws_size,
                              hipStream_t stream) {
  const float* tc       = (const float*)d_in[0];
  const float* cc       = (const float*)d_in[1];
  const float* initv    = (const float*)d_in[2];
  const float* W_cf     = (const float*)d_in[3];
  const float* b_cf     = (const float*)d_in[4];
  const float* ln_g     = (const float*)d_in[5];
  const float* ln_b     = (const float*)d_in[6];
  const float* W_feat   = (const float*)d_in[7];
  const float* b_feat   = (const float*)d_in[8];
  const float* W_inproj = (const float*)d_in[9];
  const float* b_inproj = (const float*)d_in[10];
  const float* conv_w   = (const float*)d_in[11];
  const float* conv_b   = (const float*)d_in[12];
  const float* W_xproj  = (const float*)d_in[13];
  const float* W_dt     = (const float*)d_in[14];
  const float* b_dt     = (const float*)d_in[15];
  const float* D_param  = (const float*)d_in[16];
  const float* W_out    = (const float*)d_in[17];
  const float* b_out    = (const float*)d_in[18];
  const float* W_tr     = (const float*)d_in[19];
  const float* b_tr     = (const float*)d_in[20];
  const float* W_se     = (const float*)d_in[21];
  const float* b_se     = (const float*)d_in[22];
  const float* W_fin    = (const float*)d_in[23];
  const float* b_fin    = (const float*)d_in[24];

  float* ws = (float*)d_ws;   // needs 902144 B

  hipLaunchKernelGGL(k_fold, dim3(781), dim3(256), 0, stream,
                     W_feat, W_inproj, W_out, W_tr, W_se, b_out, b_tr, b_se,
                     W_xproj, W_dt, ws);
  hipLaunchKernelGGL(k_scan, dim3(256), dim3(1024), 0, stream,
                     tc, cc, initv, W_cf, b_cf, ln_g, ln_b, W_feat, b_feat,
                     W_inproj, b_inproj, conv_w, conv_b, b_dt, D_param,
                     W_fin, b_fin, ws, (float*)d_out);
}

// Round 10
// 2187.000 us; speedup vs baseline: 1.4053x; 1.1678x over previous
//
#include <hip/hip_runtime.h>

// ws layout (float offsets) — ONE-TIME reads only (d_ws per-step streams proved
// toxic in r9: per-lane streams -> 64 lines/wave-load, 1.4GB fetch):
//   Wcx  [7][2048]  @ 0      xz-feedback fold
//   WtsT [14][1024] @ 14336  (W_out @ [W_tr|W_se])^T
//   bts  [14]       @ 28672
#define WS_WCX  0
#define WS_WTST 14336
#define WS_BTS  28672

// ---------------- one-time weight folds ----------------
__global__ __launch_bounds__(256) void k_fold(
    const float* __restrict__ W_feat, const float* __restrict__ W_inproj,
    const float* __restrict__ Wout, const float* __restrict__ Wtr,
    const float* __restrict__ Wse, const float* __restrict__ b_out,
    const float* __restrict__ b_tr, const float* __restrict__ b_se,
    float* __restrict__ ws) {
  const int b = blockIdx.x, t = threadIdx.x;
  if (b < 8) {                       // Wcx[i][j] = sum_k W_feat[512+i][k] W_inproj[k][j]
    int j = b * 256 + t;
    float acc[7] = {0, 0, 0, 0, 0, 0, 0};
    for (int k = 0; k < 512; ++k) {
      float wi = W_inproj[(size_t)k * 2048 + j];
#pragma unroll
      for (int i = 0; i < 7; ++i) acc[i] += W_feat[(size_t)(512 + i) * 512 + k] * wi;
    }
#pragma unroll
    for (int i = 0; i < 7; ++i) ws[WS_WCX + i * 2048 + j] = acc[i];
  } else if (b < 12) {               // WtsT[c][k] = sum_o Wout[k][o]*[Wtr|Wse][o][c]
    int k = (b - 8) * 256 + t;
    float acc[14];
#pragma unroll
    for (int c = 0; c < 14; ++c) acc[c] = 0.f;
    const float* wo = Wout + (size_t)k * 512;
    for (int o = 0; o < 512; ++o) {
      float w = wo[o];
      const float* tr = Wtr + o * 7;
      const float* se = Wse + o * 7;
#pragma unroll
      for (int c = 0; c < 7; ++c) { acc[c] += w * tr[c]; acc[7 + c] += w * se[c]; }
    }
#pragma unroll
    for (int c = 0; c < 14; ++c) ws[WS_WTST + c * 1024 + k] = acc[c];
  } else {                           // bts
    if (t < 14) {
      int c = (t < 7) ? t : t - 7;
      const float* W = (t < 7) ? Wtr : Wse;
      float s = (t < 7) ? b_tr[t] : b_se[t - 7];
      for (int o = 0; o < 512; ++o) s += b_out[o] * W[o * 7 + c];
      ws[WS_BTS + t] = s;
    }
  }
}

// ---------------- persistent scan: 256 blocks x 1024 thr, 4 rows/block ------
struct Pro {                        // prologue-only
  float x2[4][1024];                // 16K
  float hb[4][512];                 // 8K
  float hin[4][512];                // 8K
  float hpart[2][4][512];           // 16K
};
struct Sc {                         // scan-phase
  float xc[4][1024];                // 16K
  float part2[16][4][160];          // 40K  (16 K-chunks of 64)
  float proj[4][32];                // 512B
  float combs[4][8];
  float bcv[4];
  float ts[4][16];
};
union SMem { Pro pro; Sc sc; };

__global__ __launch_bounds__(1024) void k_scan(
    const float* __restrict__ tc, const float* __restrict__ cc,
    const float* __restrict__ initv,
    const float* __restrict__ W_cf, const float* __restrict__ b_cf,
    const float* __restrict__ ln_g, const float* __restrict__ ln_b,
    const float* __restrict__ W_feat, const float* __restrict__ b_feat,
    const float* __restrict__ W_inproj, const float* __restrict__ b_inproj,
    const float* __restrict__ conv_w, const float* __restrict__ conv_b,
    const float* __restrict__ Wxp, const float* __restrict__ Wdt,
    const float* __restrict__ b_dt, const float* __restrict__ D_param,
    const float* __restrict__ W_fin, const float* __restrict__ b_fin,
    const float* __restrict__ ws, float* __restrict__ out) {
  __shared__ SMem S;
  const int t = threadIdx.x;          // 0..1023
  const int r0 = blockIdx.x * 4;
  const int o9 = t & 511;
  const int kc9 = t >> 9;

  // ================= prologue =================
  for (int idx = t; idx < 4096; idx += 1024) {
    int r = idx >> 10, k = idx & 1023;
    S.pro.x2[r][k] = (k < 512) ? tc[(size_t)(r0 + r) * 512 + k]
                               : cc[(size_t)(r0 + r) * 512 + (k - 512)];
  }
  __syncthreads();
  // h = relu([tc,cc] @ W_cf + b_cf), K split 2x512
  {
    const float* wp = W_cf + (size_t)(kc9 * 512) * 512 + o9;
    int k0 = kc9 * 512;
    float a0 = 0, a1 = 0, a2 = 0, a3 = 0;
    for (int k = k0; k < k0 + 512; ++k) {
      float w = wp[0]; wp += 512;
      a0 += S.pro.x2[0][k] * w; a1 += S.pro.x2[1][k] * w;
      a2 += S.pro.x2[2][k] * w; a3 += S.pro.x2[3][k] * w;
    }
    S.pro.hpart[kc9][0][o9] = a0; S.pro.hpart[kc9][1][o9] = a1;
    S.pro.hpart[kc9][2][o9] = a2; S.pro.hpart[kc9][3][o9] = a3;
  }
  __syncthreads();
  {
    float b = b_cf[o9];
#pragma unroll
    for (int rr = 0; rr < 2; ++rr) {
      int r = kc9 * 2 + rr;
      S.pro.hb[r][o9] = fmaxf(S.pro.hpart[0][r][o9] + S.pro.hpart[1][r][o9] + b, 0.f);
    }
  }
  __syncthreads();
  // LayerNorm
  if (t < 256) {
    int w = t >> 6, lane = t & 63;
    float s = 0.f, s2 = 0.f;
    for (int j = lane; j < 512; j += 64) { float v = S.pro.hb[w][j]; s += v; s2 += v * v; }
#pragma unroll
    for (int off = 32; off; off >>= 1) { s += __shfl_xor(s, off); s2 += __shfl_xor(s2, off); }
    float mu = s * (1.f / 512.f);
    float var = s2 * (1.f / 512.f) - mu * mu;
    float inv = rsqrtf(var + 1e-5f);
    for (int j = lane; j < 512; j += 64)
      S.pro.hb[w][j] = (S.pro.hb[w][j] - mu) * inv * ln_g[j] + ln_b[j];
  }
  __syncthreads();
  // hin = fused @ W_feat[:512] + b_feat, K split 2x256
  {
    int k0 = kc9 * 256;
    const float* wp = W_feat + (size_t)k0 * 512 + o9;
    float a0 = 0, a1 = 0, a2 = 0, a3 = 0;
    for (int k = k0; k < k0 + 256; ++k) {
      float w = wp[0]; wp += 512;
      a0 += S.pro.hb[0][k] * w; a1 += S.pro.hb[1][k] * w;
      a2 += S.pro.hb[2][k] * w; a3 += S.pro.hb[3][k] * w;
    }
    S.pro.hpart[kc9][0][o9] = a0; S.pro.hpart[kc9][1][o9] = a1;
    S.pro.hpart[kc9][2][o9] = a2; S.pro.hpart[kc9][3][o9] = a3;
  }
  __syncthreads();
  {
    float b = b_feat[o9];
#pragma unroll
    for (int rr = 0; rr < 2; ++rr) {
      int r = kc9 * 2 + rr;
      S.pro.hin[r][o9] = S.pro.hpart[0][r][o9] + S.pro.hpart[1][r][o9] + b;
    }
  }
  __syncthreads();

  // xz_base: thread t owns cols t (x half) and 1024+t (z half), 4 rows
  float xzbx[4], xzbz[4];
#pragma unroll
  for (int half = 0; half < 2; ++half) {
    int col = t + half * 1024;
    const float* wp = W_inproj + col;
    float a0 = 0, a1 = 0, a2 = 0, a3 = 0;
    for (int k = 0; k < 512; ++k) {
      float wi = wp[0]; wp += 2048;
      a0 += S.pro.hin[0][k] * wi; a1 += S.pro.hin[1][k] * wi;
      a2 += S.pro.hin[2][k] * wi; a3 += S.pro.hin[3][k] * wi;
    }
    float bi = b_inproj[col];
    if (half == 0) { xzbx[0] = a0 + bi; xzbx[1] = a1 + bi; xzbx[2] = a2 + bi; xzbx[3] = a3 + bi; }
    else           { xzbz[0] = a0 + bi; xzbz[1] = a1 + bi; xzbz[2] = a2 + bi; xzbz[3] = a3 + bi; }
  }

  // ---- step-invariant per-thread constants (one-time ws/d_in reads) ----
  float wcxx[7], wcxz[7];
#pragma unroll
  for (int i = 0; i < 7; ++i) {
    wcxx[i] = ws[WS_WCX + i * 2048 + t];
    wcxz[i] = ws[WS_WCX + i * 2048 + 1024 + t];
  }
  const float cw3  = conv_w[t * 4 + 3];
  const float cbv  = conv_b[t];
  const float dpar = D_param[t];
  const float bdtv = b_dt[t];
  // Pts weights in registers (wave wv owns output col wv)
  const int wv = t >> 6, ln = t & 63;
  float wts[16], btsw = 0.f;
  if (wv < 14) {
#pragma unroll
    for (int i = 0; i < 16; ++i) wts[i] = ws[WS_WTST + wv * 1024 + ln + i * 64];
    btsw = ws[WS_BTS + wv];
  } else {
#pragma unroll
    for (int i = 0; i < 16; ++i) wts[i] = 0.f;
  }

  if (t < 28) S.sc.combs[t / 7][t % 7] = initv[(r0 + t / 7) * 7 + (t % 7)];
  __syncthreads();

  // ================= 64 sequential decode steps =================
  float zsr[4], xcr[4];
  for (int step = 0; step < 64; ++step) {
    // P1: xz = xz_base + comb @ Wcx; x_c = silu(conv) -> LDS+reg; silu(z) -> reg
#pragma unroll
    for (int r = 0; r < 4; ++r) {
      float v = xzbx[r], u = xzbz[r];
#pragma unroll
      for (int i = 0; i < 7; ++i) {
        float cb_ = S.sc.combs[r][i];
        v += cb_ * wcxx[i];
        u += cb_ * wcxz[i];
      }
      v = v * cw3 + cbv;
      float sv = v / (1.f + __expf(-v));
      xcr[r] = sv;
      S.sc.xc[r][t] = sv;
      zsr[r] = u / (1.f + __expf(-u));
    }
    __syncthreads();

    // P2: x_c @ Wxp. 640 thr = 16 K-chunks(64) x 40 col-quads.
    // One float4 weight load per 16 FMAs; wave reads 640B contiguous.
    if (t < 640) {
      int kc = t / 40, g = t - kc * 40;    // kc 0..15, g 0..39
      int kbase = kc * 64;
      const float4* wp = reinterpret_cast<const float4*>(Wxp + (size_t)kbase * 160 + 4 * g);
      float a00 = 0, a01 = 0, a02 = 0, a03 = 0;   // col j, row r -> a<j><r>
      float a10 = 0, a11 = 0, a12 = 0, a13 = 0;
      float a20 = 0, a21 = 0, a22 = 0, a23 = 0;
      float a30 = 0, a31 = 0, a32 = 0, a33 = 0;
#pragma unroll 4
      for (int k = 0; k < 64; ++k) {
        float4 w = wp[(size_t)k * 40];
        float x0 = S.sc.xc[0][kbase + k];
        float x1 = S.sc.xc[1][kbase + k];
        float x2 = S.sc.xc[2][kbase + k];
        float x3 = S.sc.xc[3][kbase + k];
        a00 += w.x * x0; a01 += w.x * x1; a02 += w.x * x2; a03 += w.x * x3;
        a10 += w.y * x0; a11 += w.y * x1; a12 += w.y * x2; a13 += w.y * x3;
        a20 += w.z * x0; a21 += w.z * x1; a22 += w.z * x2; a23 += w.z * x3;
        a30 += w.w * x0; a31 += w.w * x1; a32 += w.w * x2; a33 += w.w * x3;
      }
      float4* pr0 = reinterpret_cast<float4*>(&S.sc.part2[kc][0][4 * g]);
      float4* pr1 = reinterpret_cast<float4*>(&S.sc.part2[kc][1][4 * g]);
      float4* pr2 = reinterpret_cast<float4*>(&S.sc.part2[kc][2][4 * g]);
      float4* pr3 = reinterpret_cast<float4*>(&S.sc.part2[kc][3][4 * g]);
      *pr0 = make_float4(a00, a10, a20, a30);
      *pr1 = make_float4(a01, a11, a21, a31);
      *pr2 = make_float4(a02, a12, a22, a32);
      *pr3 = make_float4(a03, a13, a23, a33);
    }
    __syncthreads();

    // reduce dt_r (cols 0..31) + bc = <Bm,Cm> (cols 32..159)
    if (t < 128) {
      int r = t >> 5, p = t & 31;
      float s = 0.f;
#pragma unroll
      for (int c = 0; c < 16; ++c) s += S.sc.part2[c][r][p];
      S.sc.proj[r][p] = s;
    } else if (t >= 256 && t < 512) {
      int r = (t - 256) >> 6, n = t & 63;
      float bm = 0.f, cm = 0.f;
#pragma unroll
      for (int c = 0; c < 16; ++c) {
        bm += S.sc.part2[c][r][32 + n];
        cm += S.sc.part2[c][r][96 + n];
      }
      float pr = bm * cm;
#pragma unroll
      for (int off = 32; off; off >>= 1) pr += __shfl_xor(pr, off);
      if (n == 0) S.sc.bcv[r] = pr;
    }
    __syncthreads();

    // P3: dt = softplus(dt_r @ W_dt + b_dt); y = (dt*bc + D)*x_c*silu(z) -> xc
    {
      const float* wp = Wdt + t;
      const float2* p0 = reinterpret_cast<const float2*>(&S.sc.proj[0][0]);
      const float2* p1 = reinterpret_cast<const float2*>(&S.sc.proj[1][0]);
      const float2* p2 = reinterpret_cast<const float2*>(&S.sc.proj[2][0]);
      const float2* p3 = reinterpret_cast<const float2*>(&S.sc.proj[3][0]);
      float a0 = bdtv, a1 = bdtv, a2 = bdtv, a3 = bdtv;
#pragma unroll
      for (int q2 = 0; q2 < 16; ++q2) {
        float w0 = wp[0], w1 = wp[1024];
        wp += 2048;
        float2 q0 = p0[q2], q1 = p1[q2], q2v = p2[q2], q3 = p3[q2];
        a0 += q0.x * w0 + q0.y * w1;
        a1 += q1.x * w0 + q1.y * w1;
        a2 += q2v.x * w0 + q2v.y * w1;
        a3 += q3.x * w0 + q3.y * w1;
      }
      float accs[4] = {a0, a1, a2, a3};
#pragma unroll
      for (int r = 0; r < 4; ++r) {
        float v = accs[r];
        float sp = fmaxf(v, 0.f) + log1pf(__expf(-fabsf(v)));
        S.sc.xc[r][t] = (sp * S.sc.bcv[r] + dpar) * xcr[r] * zsr[r];
      }
    }
    __syncthreads();

    // Pts: ts = y @ Wts + bts (weights in registers)
    if (wv < 14) {
      float a0 = 0, a1 = 0, a2 = 0, a3 = 0;
#pragma unroll
      for (int i = 0; i < 16; ++i) {
        int k = ln + i * 64;
        float wt = wts[i];
        a0 += S.sc.xc[0][k] * wt; a1 += S.sc.xc[1][k] * wt;
        a2 += S.sc.xc[2][k] * wt; a3 += S.sc.xc[3][k] * wt;
      }
#pragma unroll
      for (int off = 32; off; off >>= 1) {
        a0 += __shfl_xor(a0, off); a1 += __shfl_xor(a1, off);
        a2 += __shfl_xor(a2, off); a3 += __shfl_xor(a3, off);
      }
      if (ln == 0) {
        float v0 = a0 + btsw, v1 = a1 + btsw, v2 = a2 + btsw, v3 = a3 + btsw;
        S.sc.ts[0][wv] = v0; S.sc.ts[1][wv] = v1;
        S.sc.ts[2][wv] = v2; S.sc.ts[3][wv] = v3;
        float vals[4] = {v0, v1, v2, v3};
#pragma unroll
        for (int r = 0; r < 4; ++r) {
          size_t idx = ((size_t)(r0 + r) * 64 + step) * 7;
          if (wv < 7) out[idx + wv] = vals[r];
          else out[458752 + idx + (wv - 7)] = vals[r];
        }
      }
    }
    __syncthreads();

    // P7: comb = [trend,seas] @ W_fin + b_fin, write out + feedback
    if (t < 28) {
      int r = t / 7, c = t - (t / 7) * 7;
      float s = b_fin[c];
#pragma unroll
      for (int i = 0; i < 14; ++i) s += S.sc.ts[r][i] * W_fin[i * 7 + c];
      S.sc.combs[r][c] = s;
      out[917504 + ((size_t)(r0 + r) * 64 + step) * 7 + c] = s;
    }
    __syncthreads();
  }
}

extern "C" void kernel_launch(void* const* d_in, const int* in_sizes, int n_in,
                              void* d_out, int out_size, void* d_ws, size_t ws_size,
                              hipStream_t stream) {
  const float* tc       = (const float*)d_in[0];
  const float* cc       = (const float*)d_in[1];
  const float* initv    = (const float*)d_in[2];
  const float* W_cf     = (const float*)d_in[3];
  const float* b_cf     = (const float*)d_in[4];
  const float* ln_g     = (const float*)d_in[5];
  const float* ln_b     = (const float*)d_in[6];
  const float* W_feat   = (const float*)d_in[7];
  const float* b_feat   = (const float*)d_in[8];
  const float* W_inproj = (const float*)d_in[9];
  const float* b_inproj = (const float*)d_in[10];
  const float* conv_w   = (const float*)d_in[11];
  const float* conv_b   = (const float*)d_in[12];
  const float* W_xproj  = (const float*)d_in[13];
  const float* W_dt     = (const float*)d_in[14];
  const float* b_dt     = (const float*)d_in[15];
  const float* D_param  = (const float*)d_in[16];
  const float* W_out    = (const float*)d_in[17];
  const float* b_out    = (const float*)d_in[18];
  const float* W_tr     = (const float*)d_in[19];
  const float* b_tr     = (const float*)d_in[20];
  const float* W_se     = (const float*)d_in[21];
  const float* b_se     = (const float*)d_in[22];
  const float* W_fin    = (const float*)d_in[23];
  const float* b_fin    = (const float*)d_in[24];

  float* ws = (float*)d_ws;   // needs 114744 B

  hipLaunchKernelGGL(k_fold, dim3(13), dim3(256), 0, stream,
                     W_feat, W_inproj, W_out, W_tr, W_se, b_out, b_tr, b_se, ws);
  hipLaunchKernelGGL(k_scan, dim3(256), dim3(1024), 0, stream,
                     tc, cc, initv, W_cf, b_cf, ln_g, ln_b, W_feat, b_feat,
                     W_inproj, b_inproj, conv_w, conv_b, W_xproj, W_dt,
                     b_dt, D_param, W_fin, b_fin, ws, (float*)d_out);
}

// Round 11
// 2114.795 us; speedup vs baseline: 1.4533x; 1.0341x over previous
//
#include <hip/hip_runtime.h>

// ws layout (float offsets) — ONE-TIME reads only:
//   Wcx  [7][2048]  @ 0      xz-feedback fold
//   WtsT [14][1024] @ 14336  (W_out @ [W_tr|W_se])^T
//   bts  [14]       @ 28672
#define WS_WCX  0
#define WS_WTST 14336
#define WS_BTS  28672

// ---------------- one-time weight folds ----------------
__global__ __launch_bounds__(256) void k_fold(
    const float* __restrict__ W_feat, const float* __restrict__ W_inproj,
    const float* __restrict__ Wout, const float* __restrict__ Wtr,
    const float* __restrict__ Wse, const float* __restrict__ b_out,
    const float* __restrict__ b_tr, const float* __restrict__ b_se,
    float* __restrict__ ws) {
  const int b = blockIdx.x, t = threadIdx.x;
  if (b < 8) {                       // Wcx[i][j] = sum_k W_feat[512+i][k] W_inproj[k][j]
    int j = b * 256 + t;
    float acc[7] = {0, 0, 0, 0, 0, 0, 0};
    for (int k = 0; k < 512; ++k) {
      float wi = W_inproj[(size_t)k * 2048 + j];
#pragma unroll
      for (int i = 0; i < 7; ++i) acc[i] += W_feat[(size_t)(512 + i) * 512 + k] * wi;
    }
#pragma unroll
    for (int i = 0; i < 7; ++i) ws[WS_WCX + i * 2048 + j] = acc[i];
  } else if (b < 12) {               // WtsT[c][k] = sum_o Wout[k][o]*[Wtr|Wse][o][c]
    int k = (b - 8) * 256 + t;
    float acc[14];
#pragma unroll
    for (int c = 0; c < 14; ++c) acc[c] = 0.f;
    const float* wo = Wout + (size_t)k * 512;
    for (int o = 0; o < 512; ++o) {
      float w = wo[o];
      const float* tr = Wtr + o * 7;
      const float* se = Wse + o * 7;
#pragma unroll
      for (int c = 0; c < 7; ++c) { acc[c] += w * tr[c]; acc[7 + c] += w * se[c]; }
    }
#pragma unroll
    for (int c = 0; c < 14; ++c) ws[WS_WTST + c * 1024 + k] = acc[c];
  } else {                           // bts
    if (t < 14) {
      int c = (t < 7) ? t : t - 7;
      const float* W = (t < 7) ? Wtr : Wse;
      float s = (t < 7) ? b_tr[t] : b_se[t - 7];
      for (int o = 0; o < 512; ++o) s += b_out[o] * W[o * 7 + c];
      ws[WS_BTS + t] = s;
    }
  }
}

// ---------------- persistent scan: 512 blocks x 1024 thr, 2 rows/block ------
// LDS ~30KB -> 2 blocks/CU (grid 512 on 256 CUs) = 32 waves/CU.
struct Pro {                        // prologue-only
  float x2[2][1024];                // 8K
  float hb[2][512];                 // 4K
  float hin[2][512];                // 4K
  float hpart[2][2][512];           // 8K
};
struct Sc {                         // scan-phase
  float xc[2][1024];                // 8K
  float part2[16][2][160];          // 20K  (16 K-chunks of 64)
  float proj[2][32];                // 256B
  float combs[2][8];
  float bcv[2];
  float ts[2][16];
};
union SMem { Pro pro; Sc sc; };

__global__ __launch_bounds__(1024) void k_scan(
    const float* __restrict__ tc, const float* __restrict__ cc,
    const float* __restrict__ initv,
    const float* __restrict__ W_cf, const float* __restrict__ b_cf,
    const float* __restrict__ ln_g, const float* __restrict__ ln_b,
    const float* __restrict__ W_feat, const float* __restrict__ b_feat,
    const float* __restrict__ W_inproj, const float* __restrict__ b_inproj,
    const float* __restrict__ conv_w, const float* __restrict__ conv_b,
    const float* __restrict__ Wxp, const float* __restrict__ Wdt,
    const float* __restrict__ b_dt, const float* __restrict__ D_param,
    const float* __restrict__ W_fin, const float* __restrict__ b_fin,
    const float* __restrict__ ws, float* __restrict__ out) {
  __shared__ SMem S;
  const int t = threadIdx.x;          // 0..1023
  const int r0 = blockIdx.x * 2;
  const int o9 = t & 511;
  const int kc9 = t >> 9;

  // ================= prologue =================
  for (int idx = t; idx < 2048; idx += 1024) {
    int r = idx >> 10, k = idx & 1023;
    S.pro.x2[r][k] = (k < 512) ? tc[(size_t)(r0 + r) * 512 + k]
                               : cc[(size_t)(r0 + r) * 512 + (k - 512)];
  }
  __syncthreads();
  // h = relu([tc,cc] @ W_cf + b_cf), K split 2x512
  {
    const float* wp = W_cf + (size_t)(kc9 * 512) * 512 + o9;
    int k0 = kc9 * 512;
    float a0 = 0, a1 = 0;
    for (int k = k0; k < k0 + 512; ++k) {
      float w = wp[0]; wp += 512;
      a0 += S.pro.x2[0][k] * w; a1 += S.pro.x2[1][k] * w;
    }
    S.pro.hpart[kc9][0][o9] = a0; S.pro.hpart[kc9][1][o9] = a1;
  }
  __syncthreads();
  S.pro.hb[kc9][o9] = fmaxf(S.pro.hpart[0][kc9][o9] + S.pro.hpart[1][kc9][o9] + b_cf[o9], 0.f);
  __syncthreads();
  // LayerNorm
  if (t < 128) {
    int w = t >> 6, lane = t & 63;
    float s = 0.f, s2 = 0.f;
    for (int j = lane; j < 512; j += 64) { float v = S.pro.hb[w][j]; s += v; s2 += v * v; }
#pragma unroll
    for (int off = 32; off; off >>= 1) { s += __shfl_xor(s, off); s2 += __shfl_xor(s2, off); }
    float mu = s * (1.f / 512.f);
    float var = s2 * (1.f / 512.f) - mu * mu;
    float inv = rsqrtf(var + 1e-5f);
    for (int j = lane; j < 512; j += 64)
      S.pro.hb[w][j] = (S.pro.hb[w][j] - mu) * inv * ln_g[j] + ln_b[j];
  }
  __syncthreads();
  // hin = fused @ W_feat[:512] + b_feat, K split 2x256
  {
    int k0 = kc9 * 256;
    const float* wp = W_feat + (size_t)k0 * 512 + o9;
    float a0 = 0, a1 = 0;
    for (int k = k0; k < k0 + 256; ++k) {
      float w = wp[0]; wp += 512;
      a0 += S.pro.hb[0][k] * w; a1 += S.pro.hb[1][k] * w;
    }
    S.pro.hpart[kc9][0][o9] = a0; S.pro.hpart[kc9][1][o9] = a1;
  }
  __syncthreads();
  S.pro.hin[kc9][o9] = S.pro.hpart[0][kc9][o9] + S.pro.hpart[1][kc9][o9] + b_feat[o9];
  __syncthreads();

  // xz_base: thread t owns cols t (x half) and 1024+t (z half)
  float xzbx[2], xzbz[2];
#pragma unroll
  for (int half = 0; half < 2; ++half) {
    int col = t + half * 1024;
    const float* wp = W_inproj + col;
    float a0 = 0, a1 = 0;
    for (int k = 0; k < 512; ++k) {
      float wi = wp[0]; wp += 2048;
      a0 += S.pro.hin[0][k] * wi; a1 += S.pro.hin[1][k] * wi;
    }
    float bi = b_inproj[col];
    if (half == 0) { xzbx[0] = a0 + bi; xzbx[1] = a1 + bi; }
    else           { xzbz[0] = a0 + bi; xzbz[1] = a1 + bi; }
  }

  // ---- step-invariant per-thread constants (one-time ws/d_in reads) ----
  float wcxx[7], wcxz[7];
#pragma unroll
  for (int i = 0; i < 7; ++i) {
    wcxx[i] = ws[WS_WCX + i * 2048 + t];
    wcxz[i] = ws[WS_WCX + i * 2048 + 1024 + t];
  }
  const float cw3  = conv_w[t * 4 + 3];
  const float cbv  = conv_b[t];
  const float dpar = D_param[t];
  const float bdtv = b_dt[t];
  // Pts weights in registers (wave wv owns output col wv)
  const int wv = t >> 6, ln = t & 63;
  float wts[16], btsw = 0.f;
  if (wv < 14) {
#pragma unroll
    for (int i = 0; i < 16; ++i) wts[i] = ws[WS_WTST + wv * 1024 + ln + i * 64];
    btsw = ws[WS_BTS + wv];
  } else {
#pragma unroll
    for (int i = 0; i < 16; ++i) wts[i] = 0.f;
  }

  if (t < 14) S.sc.combs[t / 7][t % 7] = initv[(r0 + t / 7) * 7 + (t % 7)];
  __syncthreads();

  // ================= 64 sequential decode steps =================
  float zsr[2], xcr[2];
  for (int step = 0; step < 64; ++step) {
    // P1: xz = xz_base + comb @ Wcx; x_c = silu(conv) -> LDS+reg; silu(z) -> reg
#pragma unroll
    for (int r = 0; r < 2; ++r) {
      float v = xzbx[r], u = xzbz[r];
#pragma unroll
      for (int i = 0; i < 7; ++i) {
        float cb_ = S.sc.combs[r][i];
        v += cb_ * wcxx[i];
        u += cb_ * wcxz[i];
      }
      v = v * cw3 + cbv;
      float sv = v / (1.f + __expf(-v));
      xcr[r] = sv;
      S.sc.xc[r][t] = sv;
      zsr[r] = u / (1.f + __expf(-u));
    }
    __syncthreads();

    // P2: x_c @ Wxp. 640 thr = 16 K-chunks(64) x 40 col-quads.
    if (t < 640) {
      int kc = t / 40, g = t - kc * 40;    // kc 0..15, g 0..39
      int kbase = kc * 64;
      const float4* wp = reinterpret_cast<const float4*>(Wxp + (size_t)kbase * 160 + 4 * g);
      float a00 = 0, a01 = 0;    // a<col><row>
      float a10 = 0, a11 = 0;
      float a20 = 0, a21 = 0;
      float a30 = 0, a31 = 0;
#pragma unroll 4
      for (int k = 0; k < 64; ++k) {
        float4 w = wp[(size_t)k * 40];
        float x0 = S.sc.xc[0][kbase + k];
        float x1 = S.sc.xc[1][kbase + k];
        a00 += w.x * x0; a01 += w.x * x1;
        a10 += w.y * x0; a11 += w.y * x1;
        a20 += w.z * x0; a21 += w.z * x1;
        a30 += w.w * x0; a31 += w.w * x1;
      }
      float4* pr0 = reinterpret_cast<float4*>(&S.sc.part2[kc][0][4 * g]);
      float4* pr1 = reinterpret_cast<float4*>(&S.sc.part2[kc][1][4 * g]);
      *pr0 = make_float4(a00, a10, a20, a30);
      *pr1 = make_float4(a01, a11, a21, a31);
    }
    __syncthreads();

    // reduce dt_r (cols 0..31) + bc = <Bm,Cm> (cols 32..159)
    if (t < 64) {
      int r = t >> 5, p = t & 31;
      float s = 0.f;
#pragma unroll
      for (int c = 0; c < 16; ++c) s += S.sc.part2[c][r][p];
      S.sc.proj[r][p] = s;
    } else if (t >= 256 && t < 384) {
      int r = (t - 256) >> 6, n = t & 63;
      float bm = 0.f, cm = 0.f;
#pragma unroll
      for (int c = 0; c < 16; ++c) {
        bm += S.sc.part2[c][r][32 + n];
        cm += S.sc.part2[c][r][96 + n];
      }
      float pr = bm * cm;
#pragma unroll
      for (int off = 32; off; off >>= 1) pr += __shfl_xor(pr, off);
      if (n == 0) S.sc.bcv[r] = pr;
    }
    __syncthreads();

    // P3: dt = softplus(dt_r @ W_dt + b_dt); y = (dt*bc + D)*x_c*silu(z) -> xc
    {
      const float* wp = Wdt + t;
      const float2* p0 = reinterpret_cast<const float2*>(&S.sc.proj[0][0]);
      const float2* p1 = reinterpret_cast<const float2*>(&S.sc.proj[1][0]);
      float a0 = bdtv, a1 = bdtv;
#pragma unroll
      for (int q2 = 0; q2 < 16; ++q2) {
        float w0 = wp[0], w1 = wp[1024];
        wp += 2048;
        float2 q0 = p0[q2], q1 = p1[q2];
        a0 += q0.x * w0 + q0.y * w1;
        a1 += q1.x * w0 + q1.y * w1;
      }
      float accs[2] = {a0, a1};
#pragma unroll
      for (int r = 0; r < 2; ++r) {
        float v = accs[r];
        float sp = fmaxf(v, 0.f) + log1pf(__expf(-fabsf(v)));
        S.sc.xc[r][t] = (sp * S.sc.bcv[r] + dpar) * xcr[r] * zsr[r];
      }
    }
    __syncthreads();

    // Pts: ts = y @ Wts + bts (weights in registers)
    if (wv < 14) {
      float a0 = 0, a1 = 0;
#pragma unroll
      for (int i = 0; i < 16; ++i) {
        int k = ln + i * 64;
        float wt = wts[i];
        a0 += S.sc.xc[0][k] * wt; a1 += S.sc.xc[1][k] * wt;
      }
#pragma unroll
      for (int off = 32; off; off >>= 1) {
        a0 += __shfl_xor(a0, off); a1 += __shfl_xor(a1, off);
      }
      if (ln == 0) {
        float v0 = a0 + btsw, v1 = a1 + btsw;
        S.sc.ts[0][wv] = v0; S.sc.ts[1][wv] = v1;
        size_t i0 = ((size_t)(r0 + 0) * 64 + step) * 7;
        size_t i1 = ((size_t)(r0 + 1) * 64 + step) * 7;
        if (wv < 7) { out[i0 + wv] = v0; out[i1 + wv] = v1; }
        else { out[458752 + i0 + (wv - 7)] = v0; out[458752 + i1 + (wv - 7)] = v1; }
      }
    }
    __syncthreads();

    // P7: comb = [trend,seas] @ W_fin + b_fin, write out + feedback
    if (t < 14) {
      int r = t / 7, c = t - (t / 7) * 7;
      float s = b_fin[c];
#pragma unroll
      for (int i = 0; i < 14; ++i) s += S.sc.ts[r][i] * W_fin[i * 7 + c];
      S.sc.combs[r][c] = s;
      out[917504 + ((size_t)(r0 + r) * 64 + step) * 7 + c] = s;
    }
    __syncthreads();
  }
}

extern "C" void kernel_launch(void* const* d_in, const int* in_sizes, int n_in,
                              void* d_out, int out_size, void* d_ws, size_t ws_size,
                              hipStream_t stream) {
  const float* tc       = (const float*)d_in[0];
  const float* cc       = (const float*)d_in[1];
  const float* initv    = (const float*)d_in[2];
  const float* W_cf     = (const float*)d_in[3];
  const float* b_cf     = (const float*)d_in[4];
  const float* ln_g     = (const float*)d_in[5];
  const float* ln_b     = (const float*)d_in[6];
  const float* W_feat   = (const float*)d_in[7];
  const float* b_feat   = (const float*)d_in[8];
  const float* W_inproj = (const float*)d_in[9];
  const float* b_inproj = (const float*)d_in[10];
  const float* conv_w   = (const float*)d_in[11];
  const float* conv_b   = (const float*)d_in[12];
  const float* W_xproj  = (const float*)d_in[13];
  const float* W_dt     = (const float*)d_in[14];
  const float* b_dt     = (const float*)d_in[15];
  const float* D_param  = (const float*)d_in[16];
  const float* W_out    = (const float*)d_in[17];
  const float* b_out    = (const float*)d_in[18];
  const float* W_tr     = (const float*)d_in[19];
  const float* b_tr     = (const float*)d_in[20];
  const float* W_se     = (const float*)d_in[21];
  const float* b_se     = (const float*)d_in[22];
  const float* W_fin    = (const float*)d_in[23];
  const float* b_fin    = (const float*)d_in[24];

  float* ws = (float*)d_ws;   // needs 114744 B

  hipLaunchKernelGGL(k_fold, dim3(13), dim3(256), 0, stream,
                     W_feat, W_inproj, W_out, W_tr, W_se, b_out, b_tr, b_se, ws);
  hipLaunchKernelGGL(k_scan, dim3(512), dim3(1024), 0, stream,
                     tc, cc, initv, W_cf, b_cf, ln_g, ln_b, W_feat, b_feat,
                     W_inproj, b_inproj, conv_w, conv_b, W_xproj, W_dt,
                     b_dt, D_param, W_fin, b_fin, ws, (float*)d_out);
}